// Round 7
// baseline (269.684 us; speedup 1.0000x reference)
//
#include <hip/hip_runtime.h>
#include <stdint.h>

// UKF (affine motion => exact Kalman filter). Inputs fp32, outputs fp32.
//
// R6 result: octet-redundancy fixed write amplification (288->165 MB, 1.145x)
// but dur=113us with VALU 37% / HBM 21% / occ 16% => parallelism-bound
// (grid pinned at B*8 threads = 8 waves/CU).
// R7 design: checkpoint the serial chain (14 floats per 32 steps) in a
// store-free phase A, then phase B replays 32-step windows with 4x more
// waves (B*8*NW threads = 32/CU), keeping R6's 128B-contiguous flushes.
// Replay executes bitwise-identical fp ops => absmax unchanged.

static constexpr float DTc = 0.1f;

struct KF {
    float x0, x1, x2, x3;
    float p00, p01, p02, p03, p11, p12, p13, p22, p23, p33;
};
struct Consts {
    float q00, q01, q02, q03, q11, q12, q13, q22, q23, q33;
    float R00, R01, R10, R11;
};

__device__ __forceinline__ void load_consts(Consts& c, const float* Qp, const float* Rp) {
    const float4* pq = reinterpret_cast<const float4*>(Qp);
    float4 r0 = pq[0], r1 = pq[1], r2 = pq[2], r3 = pq[3];
    c.q00 = r0.x; c.q01 = r0.y; c.q02 = r0.z; c.q03 = r0.w;
    c.q11 = r1.y; c.q12 = r1.z; c.q13 = r1.w;
    c.q22 = r2.z; c.q23 = r2.w; c.q33 = r3.w;
    float4 r = *reinterpret_cast<const float4*>(Rp);
    c.R00 = r.x; c.R01 = r.y; c.R10 = r.z; c.R11 = r.w;
}

__device__ __forceinline__ void load_init(KF& s, const float* stin, const float* covin, int b) {
    float4 s4 = *reinterpret_cast<const float4*>(stin + (size_t)b * 4);
    s.x0 = s4.x; s.x1 = s4.y; s.x2 = s4.z; s.x3 = s4.w;
    const float4* pc = reinterpret_cast<const float4*>(covin + (size_t)b * 16);
    float4 r0 = pc[0], r1 = pc[1], r2 = pc[2], r3 = pc[3];
    s.p00 = r0.x; s.p01 = r0.y; s.p02 = r0.z; s.p03 = r0.w;
    s.p11 = r1.y; s.p12 = r1.z; s.p13 = r1.w;
    s.p22 = r2.z; s.p23 = r2.w; s.p33 = r3.w;
}

// one KF step; outputs predicted mean components (needed for preds output)
__device__ __forceinline__ void kf_step(KF& s, const Consts& c,
                                        float z0, float z1, float ux, float uy,
                                        float& xp0o, float& xp1o) {
    const float xp0 = s.x0 + DTc * s.x2 + 0.5f * ux * DTc * DTc;
    const float xp1 = s.x1 + DTc * s.x3 + 0.5f * uy * DTc * DTc;
    const float xp2 = s.x2 + DTc * ux;
    const float xp3 = s.x3 + DTc * uy;

    const float FP00 = s.p00 + DTc * s.p02, FP01 = s.p01 + DTc * s.p12;
    const float FP02 = s.p02 + DTc * s.p22, FP03 = s.p03 + DTc * s.p23;
    const float FP11 = s.p11 + DTc * s.p13, FP12 = s.p12 + DTc * s.p23;
    const float FP13 = s.p13 + DTc * s.p33;

    const float a00 = FP00 + DTc * FP02, a01 = FP01 + DTc * FP03;
    const float a02 = FP02, a03 = FP03;
    const float a11 = FP11 + DTc * FP13, a12 = FP12, a13 = FP13;
    const float a22 = s.p22, a23 = s.p23, a33 = s.p33;

    const float s00 = a00 + c.R00, s01 = a01 + c.R01;
    const float s10 = a01 + c.R10, s11 = a11 + c.R11;
    const float rdet = 1.0f / (s00 * s11 - s01 * s10);
    const float i00 =  s11 * rdet, i01 = -s01 * rdet;
    const float i10 = -s10 * rdet, i11 =  s00 * rdet;

    const float K00 = a00*i00 + a01*i10, K01 = a00*i01 + a01*i11;
    const float K10 = a01*i00 + a11*i10, K11 = a01*i01 + a11*i11;
    const float K20 = a02*i00 + a12*i10, K21 = a02*i01 + a12*i11;
    const float K30 = a03*i00 + a13*i10, K31 = a03*i01 + a13*i11;

    const float in0 = z0 - xp0, in1 = z1 - xp1;
    s.x0 = xp0 + K00*in0 + K01*in1;
    s.x1 = xp1 + K10*in0 + K11*in1;
    s.x2 = xp2 + K20*in0 + K21*in1;
    s.x3 = xp3 + K30*in0 + K31*in1;

    const float M00 = K00*s00 + K01*s10, M01 = K00*s01 + K01*s11;
    const float M10 = K10*s00 + K11*s10, M11 = K10*s01 + K11*s11;
    const float M20 = K20*s00 + K21*s10, M21 = K20*s01 + K21*s11;
    const float M30 = K30*s00 + K31*s10, M31 = K30*s01 + K31*s11;

    s.p00 = (a00+c.q00) - (M00*K00 + M01*K01);
    s.p01 = (a01+c.q01) - (M00*K10 + M01*K11);
    s.p02 = (a02+c.q02) - (M00*K20 + M01*K21);
    s.p03 = (a03+c.q03) - (M00*K30 + M01*K31);
    s.p11 = (a11+c.q11) - (M10*K10 + M11*K11);
    s.p12 = (a12+c.q12) - (M10*K20 + M11*K21);
    s.p13 = (a13+c.q13) - (M10*K30 + M11*K31);
    s.p22 = (a22+c.q22) - (M20*K20 + M21*K21);
    s.p23 = (a23+c.q23) - (M20*K30 + M21*K31);
    s.p33 = (a33+c.q33) - (M30*K30 + M31*K31);

    xp0o = xp0; xp1o = xp1;
}

// ---------------- Phase A: serial chain, checkpoints only ----------------
__global__ __launch_bounds__(256) void ukf_chk(
    const float* __restrict__ meas, const float* __restrict__ stin,
    const float* __restrict__ covin, const float* __restrict__ ctrl,
    const float* __restrict__ Qp, const float* __restrict__ Rp,
    float* __restrict__ ws,           // [NW-1][14][B]
    int B, int S)
{
    const int b = blockIdx.x * 256 + threadIdx.x;
    if (b >= B) return;

    KF s; Consts cc;
    load_init(s, stin, covin, b);
    load_consts(cc, Qp, Rp);

    const float4* pm0 = reinterpret_cast<const float4*>(meas + (size_t)b * 2 * S);
    const float4* pm1 = reinterpret_cast<const float4*>(meas + (size_t)b * 2 * S + S);
    const float4* pu  = reinterpret_cast<const float4*>(ctrl + (size_t)b * S * 2);

    const int NT = S / 4;
    float4 m0 = pm0[0], m1 = pm1[0], u0 = pu[0], u1 = pu[1];

    for (int sub = 0; sub < NT; ++sub) {
        float4 nm0 = make_float4(0,0,0,0), nm1 = nm0, nu0 = nm0, nu1 = nm0;
        if (sub + 1 < NT) {
            nm0 = pm0[sub+1]; nm1 = pm1[sub+1];
            nu0 = pu[2*sub+2]; nu1 = pu[2*sub+3];
        }
        const float zb0[4] = { m0.x, m0.y, m0.z, m0.w };
        const float zb1[4] = { m1.x, m1.y, m1.z, m1.w };
        const float uxb[4] = { u0.x, u0.z, u1.x, u1.z };
        const float uyb[4] = { u0.y, u0.w, u1.y, u1.w };
        float d0, d1;
#pragma unroll
        for (int k = 0; k < 4; ++k)
            kf_step(s, cc, zb0[k], zb1[k], uxb[k], uyb[k], d0, d1);

        const int tn = (sub + 1) * 4;
        if ((tn & 31) == 0 && tn < S) {        // checkpoint at t = 32,64,...
            float* wp = ws + (size_t)((tn >> 5) - 1) * 14 * B + b;
            wp[ 0*B] = s.x0;  wp[ 1*B] = s.x1;  wp[ 2*B] = s.x2;  wp[ 3*B] = s.x3;
            wp[ 4*B] = s.p00; wp[ 5*B] = s.p01; wp[ 6*B] = s.p02; wp[ 7*B] = s.p03;
            wp[ 8*B] = s.p11; wp[ 9*B] = s.p12; wp[10*B] = s.p13; wp[11*B] = s.p22;
            wp[12*B] = s.p23; wp[13*B] = s.p33;
        }
        m0 = nm0; m1 = nm1; u0 = nu0; u1 = nu1;
    }
}

// ------- Phase B: per-window replay + octet-staged contiguous stores -------
__global__ __launch_bounds__(256) void ukf_win(
    const float* __restrict__ meas, const float* __restrict__ stin,
    const float* __restrict__ covin, const float* __restrict__ ctrl,
    const float* __restrict__ Qp, const float* __restrict__ Rp,
    const float* __restrict__ ws,     // [NW-1][14][B]
    float* __restrict__ out,
    int B, int S, int NW)
{
    const int tid = blockIdx.x * 256 + threadIdx.x;
    const int myj = tid & 7;
    const int w   = tid >> 3;
    const int c   = w / B;            // window index
    const int b   = w - c * B;
    if (c >= NW) return;

    KF s; Consts cc;
    if (c == 0) {
        load_init(s, stin, covin, b);
    } else {
        const float* wp = ws + (size_t)(c - 1) * 14 * B + b;
        s.x0  = wp[ 0*B]; s.x1  = wp[ 1*B]; s.x2  = wp[ 2*B]; s.x3  = wp[ 3*B];
        s.p00 = wp[ 4*B]; s.p01 = wp[ 5*B]; s.p02 = wp[ 6*B]; s.p03 = wp[ 7*B];
        s.p11 = wp[ 8*B]; s.p12 = wp[ 9*B]; s.p13 = wp[10*B]; s.p22 = wp[11*B];
        s.p23 = wp[12*B]; s.p33 = wp[13*B];
    }
    load_consts(cc, Qp, Rp);

    const int NT  = S / 4;
    const int sb0 = c * 8;                            // first sub-tile of window
    const int LT  = min(8, NT - sb0);                 // sub-tiles in this window

    const float4* pm0 = reinterpret_cast<const float4*>(meas + (size_t)b * 2 * S);
    const float4* pm1 = reinterpret_cast<const float4*>(meas + (size_t)b * 2 * S + S);
    const float4* pu  = reinterpret_cast<const float4*>(ctrl + (size_t)b * S * 2);

    float* bp = out + (size_t)b * 2 * S;
    float* bs = out + (size_t)B * 2 * S + (size_t)b * 4 * S;
    float* bc = out + (size_t)B * 6 * S + (size_t)b * 16 * S;

    float4 sgp0, sgp1, sgs0, sgs1, sgs2, sgs3;
    float4 sgt[10];

    float4 m0 = pm0[sb0], m1 = pm1[sb0], u0 = pu[2*sb0], u1 = pu[2*sb0+1];

    for (int sub = 0; sub < LT; ++sub) {
        float4 nm0 = make_float4(0,0,0,0), nm1 = nm0, nu0 = nm0, nu1 = nm0;
        if (sub + 1 < LT) {
            const int t4 = sb0 + sub + 1;
            nm0 = pm0[t4]; nm1 = pm1[t4];
            nu0 = pu[2*t4]; nu1 = pu[2*t4+1];
        }
        const float zb0[4] = { m0.x, m0.y, m0.z, m0.w };
        const float zb1[4] = { m1.x, m1.y, m1.z, m1.w };
        const float uxb[4] = { u0.x, u0.z, u1.x, u1.z };
        const float uyb[4] = { u0.y, u0.w, u1.y, u1.w };

        const bool take = (sub == myj);
#pragma unroll
        for (int k = 0; k < 4; ++k) {
            float xp0, xp1;
            kf_step(s, cc, zb0[k], zb1[k], uxb[k], uyb[k], xp0, xp1);
            if (take) {
                if (k == 0) {
                    sgp0.x=xp0; sgp1.x=xp1; sgs0.x=s.x0; sgs1.x=s.x1; sgs2.x=s.x2; sgs3.x=s.x3;
                    sgt[0].x=s.p00; sgt[1].x=s.p01; sgt[2].x=s.p02; sgt[3].x=s.p03; sgt[4].x=s.p11;
                    sgt[5].x=s.p12; sgt[6].x=s.p13; sgt[7].x=s.p22; sgt[8].x=s.p23; sgt[9].x=s.p33;
                } else if (k == 1) {
                    sgp0.y=xp0; sgp1.y=xp1; sgs0.y=s.x0; sgs1.y=s.x1; sgs2.y=s.x2; sgs3.y=s.x3;
                    sgt[0].y=s.p00; sgt[1].y=s.p01; sgt[2].y=s.p02; sgt[3].y=s.p03; sgt[4].y=s.p11;
                    sgt[5].y=s.p12; sgt[6].y=s.p13; sgt[7].y=s.p22; sgt[8].y=s.p23; sgt[9].y=s.p33;
                } else if (k == 2) {
                    sgp0.z=xp0; sgp1.z=xp1; sgs0.z=s.x0; sgs1.z=s.x1; sgs2.z=s.x2; sgs3.z=s.x3;
                    sgt[0].z=s.p00; sgt[1].z=s.p01; sgt[2].z=s.p02; sgt[3].z=s.p03; sgt[4].z=s.p11;
                    sgt[5].z=s.p12; sgt[6].z=s.p13; sgt[7].z=s.p22; sgt[8].z=s.p23; sgt[9].z=s.p33;
                } else {
                    sgp0.w=xp0; sgp1.w=xp1; sgs0.w=s.x0; sgs1.w=s.x1; sgs2.w=s.x2; sgs3.w=s.x3;
                    sgt[0].w=s.p00; sgt[1].w=s.p01; sgt[2].w=s.p02; sgt[3].w=s.p03; sgt[4].w=s.p11;
                    sgt[5].w=s.p12; sgt[6].w=s.p13; sgt[7].w=s.p22; sgt[8].w=s.p23; sgt[9].w=s.p33;
                }
            }
        }
        m0 = nm0; m1 = nm1; u0 = nu0; u1 = nu1;
    }

    if (myj < LT) {   // flush: 8 lanes x 16B = 128B contiguous per (b,row)
        const int off = sb0 * 4 + myj * 4;
        *reinterpret_cast<float4*>(bp + 0 * S + off) = sgp0;
        *reinterpret_cast<float4*>(bp + 1 * S + off) = sgp1;
        *reinterpret_cast<float4*>(bs + 0 * S + off) = sgs0;
        *reinterpret_cast<float4*>(bs + 1 * S + off) = sgs1;
        *reinterpret_cast<float4*>(bs + 2 * S + off) = sgs2;
        *reinterpret_cast<float4*>(bs + 3 * S + off) = sgs3;
        const int map[16] = {0,1,2,3, 1,4,5,6, 2,5,7,8, 3,6,8,9};
#pragma unroll
        for (int r = 0; r < 16; r++)
            *reinterpret_cast<float4*>(bc + r * S + off) = sgt[map[r]];
    }
}

// ---------------- Fallback: proven R6 single-kernel octet ----------------
__global__ __launch_bounds__(256, 2) void ukf_oct(
    const float* __restrict__ meas, const float* __restrict__ stin,
    const float* __restrict__ covin, const float* __restrict__ ctrl,
    const float* __restrict__ Qp, const float* __restrict__ Rp,
    float* __restrict__ out, int B, int S)
{
    const int tid = blockIdx.x * 256 + threadIdx.x;
    const int b   = tid >> 3;
    const int myj = tid & 7;
    if (b >= B) return;

    KF s; Consts cc;
    load_init(s, stin, covin, b);
    load_consts(cc, Qp, Rp);

    const float4* pm0 = reinterpret_cast<const float4*>(meas + (size_t)b * 2 * S);
    const float4* pm1 = reinterpret_cast<const float4*>(meas + (size_t)b * 2 * S + S);
    const float4* pu  = reinterpret_cast<const float4*>(ctrl + (size_t)b * S * 2);

    float* bp = out + (size_t)b * 2 * S;
    float* bs = out + (size_t)B * 2 * S + (size_t)b * 4 * S;
    float* bc = out + (size_t)B * 6 * S + (size_t)b * 16 * S;

    const int NT = S / 4;
    float4 sgp0, sgp1, sgs0, sgs1, sgs2, sgs3;
    float4 sgt[10];
    float4 m0 = pm0[0], m1 = pm1[0], u0 = pu[0], u1 = pu[1];

    for (int sub = 0; sub < NT; ++sub) {
        float4 nm0 = make_float4(0,0,0,0), nm1 = nm0, nu0 = nm0, nu1 = nm0;
        if (sub + 1 < NT) {
            nm0 = pm0[sub+1]; nm1 = pm1[sub+1];
            nu0 = pu[2*sub+2]; nu1 = pu[2*sub+3];
        }
        const float zb0[4] = { m0.x, m0.y, m0.z, m0.w };
        const float zb1[4] = { m1.x, m1.y, m1.z, m1.w };
        const float uxb[4] = { u0.x, u0.z, u1.x, u1.z };
        const float uyb[4] = { u0.y, u0.w, u1.y, u1.w };
        const bool take = ((sub & 7) == myj);
#pragma unroll
        for (int k = 0; k < 4; ++k) {
            float xp0, xp1;
            kf_step(s, cc, zb0[k], zb1[k], uxb[k], uyb[k], xp0, xp1);
            if (take) {
                if (k == 0) {
                    sgp0.x=xp0; sgp1.x=xp1; sgs0.x=s.x0; sgs1.x=s.x1; sgs2.x=s.x2; sgs3.x=s.x3;
                    sgt[0].x=s.p00; sgt[1].x=s.p01; sgt[2].x=s.p02; sgt[3].x=s.p03; sgt[4].x=s.p11;
                    sgt[5].x=s.p12; sgt[6].x=s.p13; sgt[7].x=s.p22; sgt[8].x=s.p23; sgt[9].x=s.p33;
                } else if (k == 1) {
                    sgp0.y=xp0; sgp1.y=xp1; sgs0.y=s.x0; sgs1.y=s.x1; sgs2.y=s.x2; sgs3.y=s.x3;
                    sgt[0].y=s.p00; sgt[1].y=s.p01; sgt[2].y=s.p02; sgt[3].y=s.p03; sgt[4].y=s.p11;
                    sgt[5].y=s.p12; sgt[6].y=s.p13; sgt[7].y=s.p22; sgt[8].y=s.p23; sgt[9].y=s.p33;
                } else if (k == 2) {
                    sgp0.z=xp0; sgp1.z=xp1; sgs0.z=s.x0; sgs1.z=s.x1; sgs2.z=s.x2; sgs3.z=s.x3;
                    sgt[0].z=s.p00; sgt[1].z=s.p01; sgt[2].z=s.p02; sgt[3].z=s.p03; sgt[4].z=s.p11;
                    sgt[5].z=s.p12; sgt[6].z=s.p13; sgt[7].z=s.p22; sgt[8].z=s.p23; sgt[9].z=s.p33;
                } else {
                    sgp0.w=xp0; sgp1.w=xp1; sgs0.w=s.x0; sgs1.w=s.x1; sgs2.w=s.x2; sgs3.w=s.x3;
                    sgt[0].w=s.p00; sgt[1].w=s.p01; sgt[2].w=s.p02; sgt[3].w=s.p03; sgt[4].w=s.p11;
                    sgt[5].w=s.p12; sgt[6].w=s.p13; sgt[7].w=s.p22; sgt[8].w=s.p23; sgt[9].w=s.p33;
                }
            }
        }
        if ((sub & 7) == 7) {
            const int off = (sub & ~7) * 4 + myj * 4;
            *reinterpret_cast<float4*>(bp + 0 * S + off) = sgp0;
            *reinterpret_cast<float4*>(bp + 1 * S + off) = sgp1;
            *reinterpret_cast<float4*>(bs + 0 * S + off) = sgs0;
            *reinterpret_cast<float4*>(bs + 1 * S + off) = sgs1;
            *reinterpret_cast<float4*>(bs + 2 * S + off) = sgs2;
            *reinterpret_cast<float4*>(bs + 3 * S + off) = sgs3;
            const int map[16] = {0,1,2,3, 1,4,5,6, 2,5,7,8, 3,6,8,9};
#pragma unroll
            for (int r = 0; r < 16; r++)
                *reinterpret_cast<float4*>(bc + r * S + off) = sgt[map[r]];
        }
        m0 = nm0; m1 = nm1; u0 = nu0; u1 = nu1;
    }
    const int rem = NT & 7;
    if (rem && myj < rem) {
        const int off = (NT & ~7) * 4 + myj * 4;
        *reinterpret_cast<float4*>(bp + 0 * S + off) = sgp0;
        *reinterpret_cast<float4*>(bp + 1 * S + off) = sgp1;
        *reinterpret_cast<float4*>(bs + 0 * S + off) = sgs0;
        *reinterpret_cast<float4*>(bs + 1 * S + off) = sgs1;
        *reinterpret_cast<float4*>(bs + 2 * S + off) = sgs2;
        *reinterpret_cast<float4*>(bs + 3 * S + off) = sgs3;
        const int map[16] = {0,1,2,3, 1,4,5,6, 2,5,7,8, 3,6,8,9};
#pragma unroll
        for (int r = 0; r < 16; r++)
            *reinterpret_cast<float4*>(bc + r * S + off) = sgt[map[r]];
    }
}

extern "C" void kernel_launch(void* const* d_in, const int* in_sizes, int n_in,
                              void* d_out, int out_size, void* d_ws, size_t ws_size,
                              hipStream_t stream) {
    // Identify inputs by element count (order-robust):
    int iR = -1, iQ = -1, iMeas = -1, iCtrl = -1, iState = -1, iCov = -1;
    for (int i = 0; i < n_in; i++) {
        if (in_sizes[i] == 4 && iR < 0) iR = i;
        else if (in_sizes[i] == 16 && iQ < 0) iQ = i;
    }
    for (int i = 0; i < n_in && iMeas < 0; i++) {
        if (i == iR || i == iQ) continue;
        for (int j = i + 1; j < n_in; j++) {
            if (j == iR || j == iQ) continue;
            if (in_sizes[i] == in_sizes[j]) { iMeas = i; iCtrl = j; break; }
        }
    }
    int rem[2], nrem = 0;
    for (int i = 0; i < n_in && nrem < 2; i++) {
        if (i == iR || i == iQ || i == iMeas || i == iCtrl) continue;
        rem[nrem++] = i;
    }
    if (in_sizes[rem[0]] > in_sizes[rem[1]]) { iCov = rem[0]; iState = rem[1]; }
    else                                     { iCov = rem[1]; iState = rem[0]; }

    const float* meas  = (const float*)d_in[iMeas];
    const float* stin  = (const float*)d_in[iState];
    const float* covin = (const float*)d_in[iCov];
    const float* ctrl  = (const float*)d_in[iCtrl];
    const float* Qp    = (const float*)d_in[iQ];
    const float* Rp    = (const float*)d_in[iR];
    float* out = (float*)d_out;

    const int B = in_sizes[iState] / 4;
    const int S = in_sizes[iMeas] / (2 * B);
    const int NT = S / 4;
    const int NW = (NT + 7) / 8;                        // 32-step windows

    const size_t ws_needed = (size_t)(NW > 1 ? NW - 1 : 0) * 14 * B * 4;
    if (ws_size >= ws_needed && NW >= 1) {
        float* ws = (float*)d_ws;
        if (NW > 1)
            ukf_chk<<<dim3((B + 255) / 256), dim3(256), 0, stream>>>(
                meas, stin, covin, ctrl, Qp, Rp, ws, B, S);
        const long long total = (long long)B * 8 * NW;
        ukf_win<<<dim3((unsigned)((total + 255) / 256)), dim3(256), 0, stream>>>(
            meas, stin, covin, ctrl, Qp, Rp, ws, out, B, S, NW);
    } else {
        ukf_oct<<<dim3((B * 8 + 255) / 256), dim3(256), 0, stream>>>(
            meas, stin, covin, ctrl, Qp, Rp, out, B, S);
    }
}